// Round 2
// baseline (880.615 us; speedup 1.0000x reference)
//
#include <hip/hip_runtime.h>
#include <stdint.h>
#include <math.h>

// Problem constants (Phi3 attention block)
#define B_   2
#define S_   2048
#define H_   3072
#define NH   32
#define NKV  8
#define HD   96
#define OPSZ 4608          // NH*HD + 2*NKV*HD
#define MM   (B_*S_)       // 4096 token rows

typedef __attribute__((ext_vector_type(8))) short short8;
typedef __attribute__((ext_vector_type(4))) float floatx4;

__device__ __forceinline__ short f2bf(float f) {
    union { float f; uint32_t u; } v; v.f = f;
    uint32_t r = v.u + 0x7fffu + ((v.u >> 16) & 1u);   // RNE
    return (short)(r >> 16);
}
__device__ __forceinline__ float bf2f(short s) {
    union { uint32_t u; float f; } v; v.u = ((uint32_t)(uint16_t)s) << 16;
    return v.f;
}

// async global->LDS, 16B per lane; lds dest must be wave-uniform base + lane*16
__device__ __forceinline__ void async_load16(const void* g, void* l) {
    __builtin_amdgcn_global_load_lds(
        (const __attribute__((address_space(1))) void*)g,
        (__attribute__((address_space(3))) void*)l, 16, 0, 0);
}

// ---------------------------------------------------------------- cast fp32->bf16
__global__ void cast_f32_bf16(const float* __restrict__ src, short* __restrict__ dst, int n4) {
    int i = blockIdx.x * blockDim.x + threadIdx.x;
    int stride = gridDim.x * blockDim.x;
    const float4* s4 = (const float4*)src;
    short4* d4 = (short4*)dst;
    for (; i < n4; i += stride) {
        float4 v = s4[i];
        short4 o;
        o.x = f2bf(v.x); o.y = f2bf(v.y); o.z = f2bf(v.z); o.w = f2bf(v.w);
        d4[i] = o;
    }
}

// ---------------------------------------------------------------- GEMM  C[M,N] = A[M,K] * B[N,K]^T  (m97 structure)
// 128x128 tile, BK=32, global_load_lds width=16 staging, 2-barrier K-loop.
template<int OUT_BF16>
__global__ __launch_bounds__(256) void gemm_bt(const short* __restrict__ A, const short* __restrict__ Bm,
                                               float* __restrict__ Cf, short* __restrict__ Cb,
                                               int M, int N, int K) {
    __shared__ short la[128 * 32];   // DMA-imposed row-major [row][32k], no pad
    __shared__ short lb[128 * 32];
    const int tid  = threadIdx.x;
    const int wave = tid >> 6, lane = tid & 63;
    const int L15  = lane & 15, quad = lane >> 4;
    const int m0 = blockIdx.y * 128, n0 = blockIdx.x * 128;
    const int wm = (wave >> 1) * 64, wn = (wave & 1) * 64;

    // DMA source: wave w, instr t covers rows w*32+t*16 .. +16, lane -> (row=lane/4, chunk=lane%4)
    const int drow = wave * 32 + (lane >> 2);
    const int dcol = (lane & 3) * 8;
    const short* ga0 = A  + (size_t)(m0 + drow) * K + dcol;
    const short* ga1 = A  + (size_t)(m0 + drow + 16) * K + dcol;
    const short* gb0 = Bm + (size_t)(n0 + drow) * K + dcol;
    const short* gb1 = Bm + (size_t)(n0 + drow + 16) * K + dcol;
    short* lda0 = &la[(wave * 32) * 32];
    short* lda1 = &la[(wave * 32 + 16) * 32];
    short* ldb0 = &lb[(wave * 32) * 32];
    short* ldb1 = &lb[(wave * 32 + 16) * 32];

    floatx4 acc[4][4];
    for (int i = 0; i < 4; i++)
        for (int j = 0; j < 4; j++)
            acc[i][j] = (floatx4){0.f, 0.f, 0.f, 0.f};

    for (int k0 = 0; k0 < K; k0 += 32) {
        __syncthreads();
        async_load16(ga0 + k0, lda0);
        async_load16(ga1 + k0, lda1);
        async_load16(gb0 + k0, ldb0);
        async_load16(gb1 + k0, ldb1);
        __syncthreads();
        short8 af[4], bfr[4];
        #pragma unroll
        for (int i = 0; i < 4; i++)
            af[i] = *(const short8*)&la[(wm + i * 16 + L15) * 32 + quad * 8];
        #pragma unroll
        for (int j = 0; j < 4; j++)
            bfr[j] = *(const short8*)&lb[(wn + j * 16 + L15) * 32 + quad * 8];
        #pragma unroll
        for (int i = 0; i < 4; i++)
            #pragma unroll
            for (int j = 0; j < 4; j++)
                acc[i][j] = __builtin_amdgcn_mfma_f32_16x16x32_bf16(af[i], bfr[j], acc[i][j], 0, 0, 0);
    }

    // C/D layout: col = lane&15, row = quad*4 + reg
    #pragma unroll
    for (int i = 0; i < 4; i++)
        #pragma unroll
        for (int j = 0; j < 4; j++)
            #pragma unroll
            for (int r = 0; r < 4; r++) {
                int row = m0 + wm + i * 16 + quad * 4 + r;
                int col = n0 + wn + j * 16 + L15;
                float v = acc[i][j][r];
                if (OUT_BF16) Cb[(size_t)row * N + col] = f2bf(v);
                else          Cf[(size_t)row * N + col] = v;
            }
}

// ---------------------------------------------------------------- RoPE + reorder q,k
// Q gets (1/sqrt(96))*log2(e) folded in (flash softmax uses exp2).
__global__ void rope_reorder(const short* __restrict__ qkv, const int* __restrict__ pos_ids,
                             short* __restrict__ Q, short* __restrict__ Kc) {
    const int total = B_ * S_ * (NH + NKV) * HD;
    int idx = blockIdx.x * blockDim.x + threadIdx.x;
    int stride = gridDim.x * blockDim.x;
    for (; idx < total; idx += stride) {
        int d = idx % HD;
        int row = idx / HD;
        int h_all = row % (NH + NKV);
        int sb = row / (NH + NKV);
        int s = sb % S_;
        int b = sb / S_;
        int base = (b * S_ + s) * OPSZ;
        int off = (h_all < NH) ? (h_all * HD + d) : (H_ + (h_all - NH) * HD + d);
        float x = bf2f(qkv[base + off]);
        int delta = (d < 48) ? 48 : -48;
        float x2 = bf2f(qkv[base + off + delta]);
        int fi = d % 48;
        float inv = exp2f((float)fi * -0.2768273412f);   // 10000^(-fi/48)
        float theta = (float)pos_ids[b * S_ + s] * inv;
        float sn, cs;
        __sincosf(theta, &sn, &cs);
        float rot = (d < 48) ? -x2 : x2;
        float outv = x * cs + rot * sn;
        if (h_all < NH) {
            outv *= 0.14724438747f; // (1/sqrt(96)) * log2(e)
            Q[((size_t)(b * NH + h_all) * S_ + s) * HD + d] = f2bf(outv);
        } else {
            Kc[((size_t)(b * NKV + (h_all - NH)) * S_ + s) * HD + d] = f2bf(outv);
        }
    }
}

// ---------------------------------------------------------------- V transpose: qkv[b,s,3840+kvh*96+d] -> Vt[b,kvh,d,s]
__global__ __launch_bounds__(256) void v_transpose(const short* __restrict__ qkv, short* __restrict__ Vt) {
    __shared__ short tile[64 * 104];
    int blk = blockIdx.x;
    int st  = blk & 31;
    int kvh = (blk >> 5) & 7;
    int b   = blk >> 8;
    int s0  = st * 64;
    int tid = threadIdx.x;
    #pragma unroll
    for (int i = 0; i < 3; i++) {
        int c = tid + i * 256;               // 64 rows x 12 chunks
        int row = c / 12, col8 = c % 12;
        *(short8*)&tile[row * 104 + col8 * 8] =
            *(const short8*)(qkv + (size_t)(b * S_ + s0 + row) * OPSZ + 3840 + kvh * HD + col8 * 8);
    }
    __syncthreads();
    #pragma unroll
    for (int i = 0; i < 3; i++) {
        int c = tid + i * 256;               // 96 rows x 8 chunks
        int d = c >> 3, col8 = c & 7;
        short8 v;
        #pragma unroll
        for (int j = 0; j < 8; j++) v[j] = tile[(col8 * 8 + j) * 104 + d];
        *(short8*)(Vt + ((size_t)(b * NKV + kvh) * HD + d) * S_ + s0 + col8 * 8) = v;
    }
}

// ---------------------------------------------------------------- causal flash attention v2, GQA 4:1
// BQ=128 (4 waves x 32 q-rows), BKV=64; register-prefetch double buffer; 2 barriers/iter.
__global__ __launch_bounds__(256, 3) void flash_attn(const short* __restrict__ Q, const short* __restrict__ Kc,
                                                     const short* __restrict__ Vt, short* __restrict__ attn) {
    __shared__ short kl[64 * 104];       // K tile [kv=64][hd=96] (+8 pad -> odd 16B-group stride)
    __shared__ short vl[96 * 72];        // V tile [hd=96][kv=64] (+8 pad)
    __shared__ short pl[4][32 * 72];     // P tile per wave [q=32][kv=64] (+8 pad), wave-private
    const int qt = (gridDim.x - 1) - blockIdx.x;   // reversed: long blocks first
    const int h = blockIdx.y, b = blockIdx.z;
    const int kvh = h >> 2;
    const int q0 = qt * 128;
    const int tid = threadIdx.x, wave = tid >> 6, lane = tid & 63;
    const int L15 = lane & 15, quad = lane >> 4;

    // Q fragments: 2 m-tiles x 96 k
    short8 qf[2][3];
    #pragma unroll
    for (int mm = 0; mm < 2; mm++) {
        const short* qrow = Q + ((size_t)(b * NH + h) * S_ + q0 + wave * 32 + mm * 16 + L15) * HD;
        #pragma unroll
        for (int kk = 0; kk < 3; kk++) qf[mm][kk] = *(const short8*)(qrow + kk * 32 + quad * 8);
    }

    floatx4 o[2][6];
    float m_r[2][4], l_r[2][4];
    #pragma unroll
    for (int mm = 0; mm < 2; mm++) {
        #pragma unroll
        for (int nn = 0; nn < 6; nn++) o[mm][nn] = (floatx4){0.f, 0.f, 0.f, 0.f};
        #pragma unroll
        for (int r = 0; r < 4; r++) { m_r[mm][r] = -3.0e38f; l_r[mm][r] = 0.f; }
    }

    // staging address helpers (thread-constant parts)
    const int kc = tid;                        // chunk id base; chunks tid, tid+256, tid+512
    const short* kbase = Kc + (size_t)(b * NKV + kvh) * S_ * HD;
    const short* vbase = Vt + (size_t)(b * NKV + kvh) * HD * S_;

    const int jmax = 2 * qt + 2;
    short8 kreg[3], vreg[3];
    // preload tile 0
    #pragma unroll
    for (int i = 0; i < 3; i++) {
        int c = kc + i * 256;
        kreg[i] = *(const short8*)(kbase + (size_t)(c / 12) * HD + (c % 12) * 8);
        vreg[i] = *(const short8*)(vbase + (size_t)(c >> 3) * S_ + (c & 7) * 8);
    }

    for (int j = 0; j < jmax; j++) {
        const int kv0 = j * 64;
        __syncthreads();                       // prev iteration's LDS reads done
        #pragma unroll
        for (int i = 0; i < 3; i++) {
            int c = kc + i * 256;
            *(short8*)&kl[(c / 12) * 104 + (c % 12) * 8] = kreg[i];
            *(short8*)&vl[(c >> 3) * 72 + (c & 7) * 8] = vreg[i];
        }
        if (j + 1 < jmax) {                    // prefetch next tile; vmcnt overlaps compute
            const int nkv0 = kv0 + 64;
            #pragma unroll
            for (int i = 0; i < 3; i++) {
                int c = kc + i * 256;
                kreg[i] = *(const short8*)(kbase + (size_t)(nkv0 + c / 12) * HD + (c % 12) * 8);
                vreg[i] = *(const short8*)(vbase + (size_t)(c >> 3) * S_ + nkv0 + (c & 7) * 8);
            }
        }
        __syncthreads();                       // tiles visible

        // QK^T: K fragments read once, reused for both m-tiles
        floatx4 sacc[2][4];
        #pragma unroll
        for (int mm = 0; mm < 2; mm++)
            #pragma unroll
            for (int n = 0; n < 4; n++) sacc[mm][n] = (floatx4){0.f, 0.f, 0.f, 0.f};
        #pragma unroll
        for (int n = 0; n < 4; n++)
            #pragma unroll
            for (int kk = 0; kk < 3; kk++) {
                short8 kf = *(const short8*)&kl[(n * 16 + L15) * 104 + kk * 32 + quad * 8];
                sacc[0][n] = __builtin_amdgcn_mfma_f32_16x16x32_bf16(qf[0][kk], kf, sacc[0][n], 0, 0, 0);
                sacc[1][n] = __builtin_amdgcn_mfma_f32_16x16x32_bf16(qf[1][kk], kf, sacc[1][n], 0, 0, 0);
            }

        #pragma unroll
        for (int mm = 0; mm < 2; mm++) {
            const int tbase = q0 + wave * 32 + mm * 16;
            if (kv0 + 63 > tbase) {            // wave-uniform branch; mask kv > q
                int qr_base = tbase + quad * 4;
                #pragma unroll
                for (int n = 0; n < 4; n++) {
                    int kv = kv0 + n * 16 + L15;
                    #pragma unroll
                    for (int r = 0; r < 4; r++)
                        if (kv > qr_base + r) sacc[mm][n][r] = -3.0e38f;
                }
            }
            // online softmax in exp2 domain; row = quad*4+r, 16 cols per lane-group
            float mx[4];
            #pragma unroll
            for (int r = 0; r < 4; r++)
                mx[r] = fmaxf(fmaxf(sacc[mm][0][r], sacc[mm][1][r]), fmaxf(sacc[mm][2][r], sacc[mm][3][r]));
            #pragma unroll
            for (int off = 1; off < 16; off <<= 1)
                #pragma unroll
                for (int r = 0; r < 4; r++) mx[r] = fmaxf(mx[r], __shfl_xor(mx[r], off));
            float alpha[4], rs[4];
            #pragma unroll
            for (int r = 0; r < 4; r++) {
                float mn = fmaxf(m_r[mm][r], mx[r]);
                alpha[r] = exp2f(m_r[mm][r] - mn);
                m_r[mm][r] = mn; rs[r] = 0.f;
            }
            #pragma unroll
            for (int n = 0; n < 4; n++)
                #pragma unroll
                for (int r = 0; r < 4; r++) {
                    float p = exp2f(sacc[mm][n][r] - m_r[mm][r]);
                    sacc[mm][n][r] = p; rs[r] += p;
                }
            #pragma unroll
            for (int off = 1; off < 16; off <<= 1)
                #pragma unroll
                for (int r = 0; r < 4; r++) rs[r] += __shfl_xor(rs[r], off);
            #pragma unroll
            for (int r = 0; r < 4; r++) l_r[mm][r] = l_r[mm][r] * alpha[r] + rs[r];
            #pragma unroll
            for (int nn = 0; nn < 6; nn++)
                #pragma unroll
                for (int r = 0; r < 4; r++) o[mm][nn][r] *= alpha[r];

            // P (C-layout) -> wave-private LDS (no barrier needed; lgkmcnt only)
            #pragma unroll
            for (int n = 0; n < 4; n++)
                #pragma unroll
                for (int r = 0; r < 4; r++)
                    pl[wave][(mm * 16 + quad * 4 + r) * 72 + n * 16 + L15] = f2bf(sacc[mm][n][r]);
        }

        // PV: V fragments read once, reused for both m-tiles
        #pragma unroll
        for (int kk = 0; kk < 2; kk++) {
            short8 af0 = *(const short8*)&pl[wave][(L15) * 72 + kk * 32 + quad * 8];
            short8 af1 = *(const short8*)&pl[wave][(16 + L15) * 72 + kk * 32 + quad * 8];
            #pragma unroll
            for (int nn = 0; nn < 6; nn++) {
                short8 vf = *(const short8*)&vl[(nn * 16 + L15) * 72 + kk * 32 + quad * 8];
                o[0][nn] = __builtin_amdgcn_mfma_f32_16x16x32_bf16(af0, vf, o[0][nn], 0, 0, 0);
                o[1][nn] = __builtin_amdgcn_mfma_f32_16x16x32_bf16(af1, vf, o[1][nn], 0, 0, 0);
            }
        }
    }

    #pragma unroll
    for (int mm = 0; mm < 2; mm++) {
        float inv_l[4];
        #pragma unroll
        for (int r = 0; r < 4; r++) inv_l[r] = 1.0f / l_r[mm][r];
        #pragma unroll
        for (int nn = 0; nn < 6; nn++)
            #pragma unroll
            for (int r = 0; r < 4; r++) {
                float v = o[mm][nn][r] * inv_l[r];
                int row = q0 + wave * 32 + mm * 16 + quad * 4 + r;
                attn[((size_t)(b * S_) + row) * H_ + h * HD + nn * 16 + L15] = f2bf(v);
            }
    }
}

// ---------------------------------------------------------------- launch
extern "C" void kernel_launch(void* const* d_in, const int* in_sizes, int n_in,
                              void* d_out, int out_size, void* d_ws, size_t ws_size,
                              hipStream_t stream) {
    const float* hid  = (const float*)d_in[0];
    const int*   pos  = (const int*)d_in[1];
    const float* wqkv = (const float*)d_in[2];
    const float* wo   = (const float*)d_in[3];
    float* out = (float*)d_out;
    char* ws = (char*)d_ws;

    short* hid_b  = (short*)(ws + 0L);          // 4096*3072 bf16
    short* wqkv_b = (short*)(ws + 25165824L);   // 4608*3072 bf16
    short* wo_b   = (short*)(ws + 53477376L);   // 3072*3072 bf16
    short* qkv_b  = (short*)(ws + 72351744L);   // 4096*4608 bf16
    short* q_b    = (short*)(ws + 110100480L);  // [B,NH,S,HD] bf16
    short* k_b    = (short*)(ws + 135266304L);  // [B,NKV,S,HD] bf16
    short* vt_b   = (short*)(ws + 141557760L);  // [B,NKV,HD,S] bf16
    short* attn_b = (short*)(ws + 147849216L);  // [B,S,NH*HD] bf16

    cast_f32_bf16<<<4096, 256, 0, stream>>>(hid,  hid_b,  MM * H_ / 4);
    cast_f32_bf16<<<4096, 256, 0, stream>>>(wqkv, wqkv_b, OPSZ * H_ / 4);
    cast_f32_bf16<<<4096, 256, 0, stream>>>(wo,   wo_b,   H_ * H_ / 4);

    gemm_bt<1><<<dim3(OPSZ / 128, MM / 128), 256, 0, stream>>>(hid_b, wqkv_b, nullptr, qkv_b, MM, OPSZ, H_);

    rope_reorder<<<8192, 256, 0, stream>>>(qkv_b, pos, q_b, k_b);
    v_transpose<<<512, 256, 0, stream>>>(qkv_b, vt_b);

    flash_attn<<<dim3(S_ / 128, NH, B_), 256, 0, stream>>>(q_b, k_b, vt_b, attn_b);

    gemm_bt<0><<<dim3(H_ / 128, MM / 128), 256, 0, stream>>>(attn_b, wo_b, out, nullptr, MM, H_, H_);
}

// Round 3
// 628.053 us; speedup vs baseline: 1.4021x; 1.4021x over previous
//
#include <hip/hip_runtime.h>
#include <stdint.h>
#include <math.h>

// Problem constants (Phi3 attention block)
#define B_   2
#define S_   2048
#define H_   3072
#define NH   32
#define NKV  8
#define HD   96
#define OPSZ 4608          // NH*HD + 2*NKV*HD
#define MM   (B_*S_)       // 4096 token rows

typedef __attribute__((ext_vector_type(8))) short short8;
typedef __attribute__((ext_vector_type(4))) float floatx4;

__device__ __forceinline__ short f2bf(float f) {
    union { float f; uint32_t u; } v; v.f = f;
    uint32_t r = v.u + 0x7fffu + ((v.u >> 16) & 1u);   // RNE
    return (short)(r >> 16);
}
__device__ __forceinline__ float bf2f(short s) {
    union { uint32_t u; float f; } v; v.u = ((uint32_t)(uint16_t)s) << 16;
    return v.f;
}
__device__ __forceinline__ uint32_t pk_bf(float lo, float hi) {
    return (uint32_t)(uint16_t)f2bf(lo) | ((uint32_t)(uint16_t)f2bf(hi) << 16);
}

// async global->LDS, 16B per lane; lds dest is wave-uniform base + lane*16
__device__ __forceinline__ void async_load16(const void* g, void* l) {
    __builtin_amdgcn_global_load_lds(
        (const __attribute__((address_space(1))) void*)g,
        (__attribute__((address_space(3))) void*)l, 16, 0, 0);
}

// ---------------------------------------------------------------- cast fp32->bf16
__global__ void cast_f32_bf16(const float* __restrict__ src, short* __restrict__ dst, int n4) {
    int i = blockIdx.x * blockDim.x + threadIdx.x;
    int stride = gridDim.x * blockDim.x;
    const float4* s4 = (const float4*)src;
    short4* d4 = (short4*)dst;
    for (; i < n4; i += stride) {
        float4 v = s4[i];
        short4 o;
        o.x = f2bf(v.x); o.y = f2bf(v.y); o.z = f2bf(v.z); o.w = f2bf(v.w);
        d4[i] = o;
    }
}

// ---------------------------------------------------------------- GEMM  C[M,N] = A[M,K] * B[N,K]^T  (m97 structure)
template<int OUT_BF16>
__global__ __launch_bounds__(256) void gemm_bt(const short* __restrict__ A, const short* __restrict__ Bm,
                                               float* __restrict__ Cf, short* __restrict__ Cb,
                                               int M, int N, int K) {
    __shared__ short la[128 * 32];
    __shared__ short lb[128 * 32];
    const int tid  = threadIdx.x;
    const int wave = tid >> 6, lane = tid & 63;
    const int L15  = lane & 15, quad = lane >> 4;
    const int m0 = blockIdx.y * 128, n0 = blockIdx.x * 128;
    const int wm = (wave >> 1) * 64, wn = (wave & 1) * 64;

    const int drow = wave * 32 + (lane >> 2);
    const int dcol = (lane & 3) * 8;
    const short* ga0 = A  + (size_t)(m0 + drow) * K + dcol;
    const short* ga1 = A  + (size_t)(m0 + drow + 16) * K + dcol;
    const short* gb0 = Bm + (size_t)(n0 + drow) * K + dcol;
    const short* gb1 = Bm + (size_t)(n0 + drow + 16) * K + dcol;
    short* lda0 = &la[(wave * 32) * 32];
    short* lda1 = &la[(wave * 32 + 16) * 32];
    short* ldb0 = &lb[(wave * 32) * 32];
    short* ldb1 = &lb[(wave * 32 + 16) * 32];

    floatx4 acc[4][4];
    for (int i = 0; i < 4; i++)
        for (int j = 0; j < 4; j++)
            acc[i][j] = (floatx4){0.f, 0.f, 0.f, 0.f};

    for (int k0 = 0; k0 < K; k0 += 32) {
        __syncthreads();
        async_load16(ga0 + k0, lda0);
        async_load16(ga1 + k0, lda1);
        async_load16(gb0 + k0, ldb0);
        async_load16(gb1 + k0, ldb1);
        __syncthreads();
        short8 af[4], bfr[4];
        #pragma unroll
        for (int i = 0; i < 4; i++)
            af[i] = *(const short8*)&la[(wm + i * 16 + L15) * 32 + quad * 8];
        #pragma unroll
        for (int j = 0; j < 4; j++)
            bfr[j] = *(const short8*)&lb[(wn + j * 16 + L15) * 32 + quad * 8];
        #pragma unroll
        for (int i = 0; i < 4; i++)
            #pragma unroll
            for (int j = 0; j < 4; j++)
                acc[i][j] = __builtin_amdgcn_mfma_f32_16x16x32_bf16(af[i], bfr[j], acc[i][j], 0, 0, 0);
    }

    #pragma unroll
    for (int i = 0; i < 4; i++)
        #pragma unroll
        for (int j = 0; j < 4; j++)
            #pragma unroll
            for (int r = 0; r < 4; r++) {
                int row = m0 + wm + i * 16 + quad * 4 + r;
                int col = n0 + wn + j * 16 + L15;
                float v = acc[i][j][r];
                if (OUT_BF16) Cb[(size_t)row * N + col] = f2bf(v);
                else          Cf[(size_t)row * N + col] = v;
            }
}

// ---------------------------------------------------------------- RoPE + reorder q,k
// Q gets (1/sqrt(96))*log2(e) folded in (flash softmax uses exp2).
__global__ void rope_reorder(const short* __restrict__ qkv, const int* __restrict__ pos_ids,
                             short* __restrict__ Q, short* __restrict__ Kc) {
    const int total = B_ * S_ * (NH + NKV) * HD;
    int idx = blockIdx.x * blockDim.x + threadIdx.x;
    int stride = gridDim.x * blockDim.x;
    for (; idx < total; idx += stride) {
        int d = idx % HD;
        int row = idx / HD;
        int h_all = row % (NH + NKV);
        int sb = row / (NH + NKV);
        int s = sb % S_;
        int b = sb / S_;
        int base = (b * S_ + s) * OPSZ;
        int off = (h_all < NH) ? (h_all * HD + d) : (H_ + (h_all - NH) * HD + d);
        float x = bf2f(qkv[base + off]);
        int delta = (d < 48) ? 48 : -48;
        float x2 = bf2f(qkv[base + off + delta]);
        int fi = d % 48;
        float inv = exp2f((float)fi * -0.2768273412f);   // 10000^(-fi/48)
        float theta = (float)pos_ids[b * S_ + s] * inv;
        float sn, cs;
        __sincosf(theta, &sn, &cs);
        float rot = (d < 48) ? -x2 : x2;
        float outv = x * cs + rot * sn;
        if (h_all < NH) {
            outv *= 0.14724438747f; // (1/sqrt(96)) * log2(e)
            Q[((size_t)(b * NH + h_all) * S_ + s) * HD + d] = f2bf(outv);
        } else {
            Kc[((size_t)(b * NKV + (h_all - NH)) * S_ + s) * HD + d] = f2bf(outv);
        }
    }
}

// ---------------------------------------------------------------- V transpose + swizzle
// Vt[b,kvh][d][tile*64 + swz(d, kvl)] = V[b, tile*64+kvl, kvh, d]
// swz: perm(kvl = n*16+t) = (n>>1)*32 + 2t + (n&1), then chunk-rotate by d:
//      col = ((perm>>3) + d & 7)*8 + (perm&7)
// perm makes P-lane columns adjacent (packed u32 LDS writes); rotation makes
// the unpadded [96][64] V LDS tile bank-conflict-free for b128 fragment reads.
__global__ __launch_bounds__(256) void v_transpose(const short* __restrict__ qkv, short* __restrict__ Vt) {
    __shared__ short tile[64 * 104];
    int blk = blockIdx.x;
    int st  = blk & 31;
    int kvh = (blk >> 5) & 7;
    int b   = blk >> 8;
    int s0  = st * 64;
    int tid = threadIdx.x;
    #pragma unroll
    for (int i = 0; i < 3; i++) {
        int c = tid + i * 256;               // 64 rows x 12 chunks
        int row = c / 12, col8 = c % 12;
        *(short8*)&tile[row * 104 + col8 * 8] =
            *(const short8*)(qkv + (size_t)(b * S_ + s0 + row) * OPSZ + 3840 + kvh * HD + col8 * 8);
    }
    __syncthreads();
    #pragma unroll
    for (int i = 0; i < 3; i++) {
        int c = tid + i * 256;               // 96 rows x 8 chunks
        int d = c >> 3, col8 = c & 7;
        int chunk0 = (col8 - d) & 7;         // inverse rotation
        short8 v;
        #pragma unroll
        for (int j = 0; j < 8; j++) {
            int col0 = chunk0 * 8 + j;       // perm-space column
            int n = ((col0 >> 5) << 1) | (col0 & 1);
            int t = (col0 & 31) >> 1;
            v[j] = tile[(n * 16 + t) * 104 + d];
        }
        *(short8*)(Vt + ((size_t)(b * NKV + kvh) * HD + d) * S_ + s0 + col8 * 8) = v;
    }
}

// ---------------------------------------------------------------- causal flash attention v3
// BQ=128 (4 waves x 32 q-rows), BKV=64. DMA (global_load_lds) ping-pong K/V
// buffers, ONE barrier per iteration; DMA for tile j+1 issued at top of iter j.
// Paired q-tiles (qt, 15-qt) per block -> 512 uniform blocks = 2 blocks/CU.
__global__ __launch_bounds__(256) void flash_attn(const short* __restrict__ Q, const short* __restrict__ Kc,
                                                  const short* __restrict__ Vt, short* __restrict__ attn) {
    __shared__ short kl[2][64 * 96];     // 24.6 KB  (DMA layout, unpadded)
    __shared__ short vl[2][96 * 64];     // 24.6 KB  (DMA layout, swizzled globally)
    __shared__ short pl[4][32 * 72];     // 18.4 KB  wave-private P (+8 pad ok, regular ds ops)
    const int x = blockIdx.x, h = blockIdx.y, b = blockIdx.z;
    const int kvh = h >> 2;
    const int tid = threadIdx.x, wave = tid >> 6, lane = tid & 63;
    const int L15 = lane & 15, quad = lane >> 4;

    const short* kbase = Kc + (size_t)(b * NKV + kvh) * S_ * HD;
    const short* vbase = Vt + (size_t)(b * NKV + kvh) * HD * S_;

    // DMA lane-constant geometry: chunk ck = wave*3+i covers LDS shorts [ck*512, +512)
    const int vrow_lo = lane >> 3;           // + ck*8
    const int vcol    = (lane & 7) * 8;
    const int klane   = lane * 8;

    auto stage = [&](int kv0, int buf) {
        #pragma unroll
        for (int i = 0; i < 3; i++) {
            int ck = wave * 3 + i;
            // K tile rows kv0..kv0+63 are contiguous in Kc: flat copy
            async_load16(kbase + (size_t)kv0 * HD + ck * 512 + klane, &kl[buf][ck * 512]);
            // V tile: 96 rows (stride S_), 64 cols at kv0
            async_load16(vbase + (size_t)(ck * 8 + vrow_lo) * S_ + kv0 + vcol, &vl[buf][ck * 512]);
        }
    };

    #pragma unroll
    for (int pp = 0; pp < 2; pp++) {
        const int qt = pp ? x : (15 - x);
        const int q0 = qt * 128;
        const int jmax = 2 * qt + 2;

        short8 qf[2][3];
        #pragma unroll
        for (int mm = 0; mm < 2; mm++) {
            const short* qrow = Q + ((size_t)(b * NH + h) * S_ + q0 + wave * 32 + mm * 16 + L15) * HD;
            #pragma unroll
            for (int kk = 0; kk < 3; kk++) qf[mm][kk] = *(const short8*)(qrow + kk * 32 + quad * 8);
        }
        floatx4 o[2][6];
        float m_r[2][4], l_r[2][4];
        #pragma unroll
        for (int mm = 0; mm < 2; mm++) {
            #pragma unroll
            for (int nn = 0; nn < 6; nn++) o[mm][nn] = (floatx4){0.f, 0.f, 0.f, 0.f};
            #pragma unroll
            for (int r = 0; r < 4; r++) { m_r[mm][r] = -3.0e38f; l_r[mm][r] = 0.f; }
        }

        __syncthreads();                 // prior sub-problem's reads done
        stage(0, 0);

        for (int j = 0; j < jmax; j++) {
            const int c = j & 1;
            const int kv0 = j * 64;
            __syncthreads();             // implicit vmcnt(0): DMA(j) landed; buf 1-c free
            if (j + 1 < jmax) stage(kv0 + 64, 1 - c);

            const short* klp = kl[c];
            const short* vlp = vl[c];

            floatx4 sacc[2][4];
            #pragma unroll
            for (int mm = 0; mm < 2; mm++)
                #pragma unroll
                for (int n = 0; n < 4; n++) sacc[mm][n] = (floatx4){0.f, 0.f, 0.f, 0.f};
            #pragma unroll
            for (int n = 0; n < 4; n++)
                #pragma unroll
                for (int kk = 0; kk < 3; kk++) {
                    short8 kf = *(const short8*)&klp[(n * 16 + L15) * 96 + kk * 32 + quad * 8];
                    sacc[0][n] = __builtin_amdgcn_mfma_f32_16x16x32_bf16(qf[0][kk], kf, sacc[0][n], 0, 0, 0);
                    sacc[1][n] = __builtin_amdgcn_mfma_f32_16x16x32_bf16(qf[1][kk], kf, sacc[1][n], 0, 0, 0);
                }

            #pragma unroll
            for (int mm = 0; mm < 2; mm++) {
                const int tbase = q0 + wave * 32 + mm * 16;
                if (kv0 + 63 > tbase) {
                    int qr_base = tbase + quad * 4;
                    #pragma unroll
                    for (int n = 0; n < 4; n++) {
                        int kv = kv0 + n * 16 + L15;
                        #pragma unroll
                        for (int r = 0; r < 4; r++)
                            if (kv > qr_base + r) sacc[mm][n][r] = -3.0e38f;
                    }
                }
                float mx[4];
                #pragma unroll
                for (int r = 0; r < 4; r++)
                    mx[r] = fmaxf(fmaxf(sacc[mm][0][r], sacc[mm][1][r]), fmaxf(sacc[mm][2][r], sacc[mm][3][r]));
                #pragma unroll
                for (int off = 1; off < 16; off <<= 1)
                    #pragma unroll
                    for (int r = 0; r < 4; r++) mx[r] = fmaxf(mx[r], __shfl_xor(mx[r], off));
                float alpha[4], rs[4];
                #pragma unroll
                for (int r = 0; r < 4; r++) {
                    float mn = fmaxf(m_r[mm][r], mx[r]);
                    alpha[r] = exp2f(m_r[mm][r] - mn);
                    m_r[mm][r] = mn; rs[r] = 0.f;
                }
                #pragma unroll
                for (int n = 0; n < 4; n++)
                    #pragma unroll
                    for (int r = 0; r < 4; r++) {
                        float p = exp2f(sacc[mm][n][r] - m_r[mm][r]);
                        sacc[mm][n][r] = p; rs[r] += p;
                    }
                #pragma unroll
                for (int off = 1; off < 16; off <<= 1)
                    #pragma unroll
                    for (int r = 0; r < 4; r++) rs[r] += __shfl_xor(rs[r], off);
                #pragma unroll
                for (int r = 0; r < 4; r++) l_r[mm][r] = l_r[mm][r] * alpha[r] + rs[r];
                #pragma unroll
                for (int nn = 0; nn < 6; nn++)
                    #pragma unroll
                    for (int r = 0; r < 4; r++) o[mm][nn][r] *= alpha[r];

                // P -> wave-private LDS, perm space, packed u32 (row = mm*16+quad*4+r)
                #pragma unroll
                for (int r = 0; r < 4; r++) {
                    int row = mm * 16 + quad * 4 + r;
                    *(uint32_t*)&pl[wave][row * 72 + 2 * L15]      = pk_bf(sacc[mm][0][r], sacc[mm][1][r]);
                    *(uint32_t*)&pl[wave][row * 72 + 32 + 2 * L15] = pk_bf(sacc[mm][2][r], sacc[mm][3][r]);
                }
            }

            // PV in perm space; V rows chunk-rotated by row index (baked in Vt)
            #pragma unroll
            for (int kk = 0; kk < 2; kk++) {
                short8 af0 = *(const short8*)&pl[wave][L15 * 72 + kk * 32 + quad * 8];
                short8 af1 = *(const short8*)&pl[wave][(16 + L15) * 72 + kk * 32 + quad * 8];
                #pragma unroll
                for (int nn = 0; nn < 6; nn++) {
                    int row = nn * 16 + L15;
                    int rc = ((kk * 4 + quad + row) & 7) * 8;
                    short8 vf = *(const short8*)&vlp[row * 64 + rc];
                    o[0][nn] = __builtin_amdgcn_mfma_f32_16x16x32_bf16(af0, vf, o[0][nn], 0, 0, 0);
                    o[1][nn] = __builtin_amdgcn_mfma_f32_16x16x32_bf16(af1, vf, o[1][nn], 0, 0, 0);
                }
            }
        }

        #pragma unroll
        for (int mm = 0; mm < 2; mm++) {
            float inv_l[4];
            #pragma unroll
            for (int r = 0; r < 4; r++) inv_l[r] = 1.0f / l_r[mm][r];
            #pragma unroll
            for (int nn = 0; nn < 6; nn++)
                #pragma unroll
                for (int r = 0; r < 4; r++) {
                    float v = o[mm][nn][r] * inv_l[r];
                    int row = q0 + wave * 32 + mm * 16 + quad * 4 + r;
                    attn[((size_t)(b * S_) + row) * H_ + h * HD + nn * 16 + L15] = f2bf(v);
                }
        }
    }
}

// ---------------------------------------------------------------- launch
extern "C" void kernel_launch(void* const* d_in, const int* in_sizes, int n_in,
                              void* d_out, int out_size, void* d_ws, size_t ws_size,
                              hipStream_t stream) {
    const float* hid  = (const float*)d_in[0];
    const int*   pos  = (const int*)d_in[1];
    const float* wqkv = (const float*)d_in[2];
    const float* wo   = (const float*)d_in[3];
    float* out = (float*)d_out;
    char* ws = (char*)d_ws;

    short* hid_b  = (short*)(ws + 0L);          // 4096*3072 bf16
    short* wqkv_b = (short*)(ws + 25165824L);   // 4608*3072 bf16
    short* wo_b   = (short*)(ws + 53477376L);   // 3072*3072 bf16
    short* qkv_b  = (short*)(ws + 72351744L);   // 4096*4608 bf16
    short* q_b    = (short*)(ws + 110100480L);  // [B,NH,S,HD] bf16
    short* k_b    = (short*)(ws + 135266304L);  // [B,NKV,S,HD] bf16
    short* vt_b   = (short*)(ws + 141557760L);  // [B,NKV,HD,S] bf16 (swizzled)
    short* attn_b = (short*)(ws + 147849216L);  // [B,S,NH*HD] bf16

    cast_f32_bf16<<<4096, 256, 0, stream>>>(hid,  hid_b,  MM * H_ / 4);
    cast_f32_bf16<<<4096, 256, 0, stream>>>(wqkv, wqkv_b, OPSZ * H_ / 4);
    cast_f32_bf16<<<4096, 256, 0, stream>>>(wo,   wo_b,   H_ * H_ / 4);

    gemm_bt<1><<<dim3(OPSZ / 128, MM / 128), 256, 0, stream>>>(hid_b, wqkv_b, nullptr, qkv_b, MM, OPSZ, H_);

    rope_reorder<<<8192, 256, 0, stream>>>(qkv_b, pos, q_b, k_b);
    v_transpose<<<512, 256, 0, stream>>>(qkv_b, vt_b);

    flash_attn<<<dim3(8, NH, B_), 256, 0, stream>>>(q_b, k_b, vt_b, attn_b);

    gemm_bt<0><<<dim3(H_ / 128, MM / 128), 256, 0, stream>>>(attn_b, wo_b, out, nullptr, MM, H_, H_);
}

// Round 4
// 584.353 us; speedup vs baseline: 1.5070x; 1.0748x over previous
//
#include <hip/hip_runtime.h>
#include <stdint.h>
#include <math.h>

// Problem constants (Phi3 attention block)
#define B_   2
#define S_   2048
#define H_   3072
#define NH   32
#define NKV  8
#define HD   96
#define OPSZ 4608          // NH*HD + 2*NKV*HD
#define MM   (B_*S_)       // 4096 token rows

typedef __attribute__((ext_vector_type(8))) short short8;
typedef __attribute__((ext_vector_type(4))) float floatx4;

__device__ __forceinline__ short f2bf(float f) {
    union { float f; uint32_t u; } v; v.f = f;
    uint32_t r = v.u + 0x7fffu + ((v.u >> 16) & 1u);   // RNE
    return (short)(r >> 16);
}
__device__ __forceinline__ float bf2f(short s) {
    union { uint32_t u; float f; } v; v.u = ((uint32_t)(uint16_t)s) << 16;
    return v.f;
}
// truncating bf16x2 pack (P in [0,1]; bias <= 2^-9 rel, numerator & denominator consistent)
__device__ __forceinline__ uint32_t pk_bf_trunc(float lo, float hi) {
    union { float f; uint32_t u; } a, b; a.f = lo; b.f = hi;
    return (a.u >> 16) | (b.u & 0xFFFF0000u);
}
// raw v_exp_f32 (base-2): skips OCML denorm-fixup tail; -3e38 input -> 0
__device__ __forceinline__ float fast_exp2(float x) {
    float r;
    asm volatile("v_exp_f32 %0, %1" : "=v"(r) : "v"(x));
    return r;
}
// max over the 16 lanes of a DPP row via row_ror rotate-reduce (pure VALU)
__device__ __forceinline__ float dpp_max16(float x) {
    union { float f; int i; } a, t;
    a.f = x;
    t.i = __builtin_amdgcn_update_dpp(0, a.i, 0x128, 0xF, 0xF, false); a.f = fmaxf(a.f, t.f);
    t.i = __builtin_amdgcn_update_dpp(0, a.i, 0x124, 0xF, 0xF, false); a.f = fmaxf(a.f, t.f);
    t.i = __builtin_amdgcn_update_dpp(0, a.i, 0x122, 0xF, 0xF, false); a.f = fmaxf(a.f, t.f);
    t.i = __builtin_amdgcn_update_dpp(0, a.i, 0x121, 0xF, 0xF, false); a.f = fmaxf(a.f, t.f);
    return a.f;
}

// async global->LDS, 16B per lane; lds dest is wave-uniform base + lane*16
__device__ __forceinline__ void async_load16(const void* g, void* l) {
    __builtin_amdgcn_global_load_lds(
        (const __attribute__((address_space(1))) void*)g,
        (__attribute__((address_space(3))) void*)l, 16, 0, 0);
}

// ---------------------------------------------------------------- merged casts fp32->bf16
#define CN1 (MM * H_ / 4)
#define CN2 (OPSZ * H_ / 4)
#define CN3 (H_ * H_ / 4)
__global__ void cast3_f32_bf16(const float* __restrict__ s1, const float* __restrict__ s2,
                               const float* __restrict__ s3, short* __restrict__ d1,
                               short* __restrict__ d2, short* __restrict__ d3) {
    int gid = blockIdx.x * blockDim.x + threadIdx.x;
    int stride = gridDim.x * blockDim.x;
    for (int i = gid; i < CN1; i += stride) {
        float4 v = ((const float4*)s1)[i];
        short4 o; o.x = f2bf(v.x); o.y = f2bf(v.y); o.z = f2bf(v.z); o.w = f2bf(v.w);
        ((short4*)d1)[i] = o;
    }
    for (int i = gid; i < CN2; i += stride) {
        float4 v = ((const float4*)s2)[i];
        short4 o; o.x = f2bf(v.x); o.y = f2bf(v.y); o.z = f2bf(v.z); o.w = f2bf(v.w);
        ((short4*)d2)[i] = o;
    }
    for (int i = gid; i < CN3; i += stride) {
        float4 v = ((const float4*)s3)[i];
        short4 o; o.x = f2bf(v.x); o.y = f2bf(v.y); o.z = f2bf(v.z); o.w = f2bf(v.w);
        ((short4*)d3)[i] = o;
    }
}

// ---------------------------------------------------------------- GEMM  C[M,N] = A[M,K] * B[N,K]^T  (m97 structure)
template<int OUT_BF16>
__global__ __launch_bounds__(256) void gemm_bt(const short* __restrict__ A, const short* __restrict__ Bm,
                                               float* __restrict__ Cf, short* __restrict__ Cb,
                                               int M, int N, int K) {
    __shared__ short la[128 * 32];
    __shared__ short lb[128 * 32];
    const int tid  = threadIdx.x;
    const int wave = tid >> 6, lane = tid & 63;
    const int L15  = lane & 15, quad = lane >> 4;
    const int m0 = blockIdx.y * 128, n0 = blockIdx.x * 128;
    const int wm = (wave >> 1) * 64, wn = (wave & 1) * 64;

    const int drow = wave * 32 + (lane >> 2);
    const int dcol = (lane & 3) * 8;
    const short* ga0 = A  + (size_t)(m0 + drow) * K + dcol;
    const short* ga1 = A  + (size_t)(m0 + drow + 16) * K + dcol;
    const short* gb0 = Bm + (size_t)(n0 + drow) * K + dcol;
    const short* gb1 = Bm + (size_t)(n0 + drow + 16) * K + dcol;
    short* lda0 = &la[(wave * 32) * 32];
    short* lda1 = &la[(wave * 32 + 16) * 32];
    short* ldb0 = &lb[(wave * 32) * 32];
    short* ldb1 = &lb[(wave * 32 + 16) * 32];

    floatx4 acc[4][4];
    for (int i = 0; i < 4; i++)
        for (int j = 0; j < 4; j++)
            acc[i][j] = (floatx4){0.f, 0.f, 0.f, 0.f};

    for (int k0 = 0; k0 < K; k0 += 32) {
        __syncthreads();
        async_load16(ga0 + k0, lda0);
        async_load16(ga1 + k0, lda1);
        async_load16(gb0 + k0, ldb0);
        async_load16(gb1 + k0, ldb1);
        __syncthreads();
        short8 af[4], bfr[4];
        #pragma unroll
        for (int i = 0; i < 4; i++)
            af[i] = *(const short8*)&la[(wm + i * 16 + L15) * 32 + quad * 8];
        #pragma unroll
        for (int j = 0; j < 4; j++)
            bfr[j] = *(const short8*)&lb[(wn + j * 16 + L15) * 32 + quad * 8];
        #pragma unroll
        for (int i = 0; i < 4; i++)
            #pragma unroll
            for (int j = 0; j < 4; j++)
                acc[i][j] = __builtin_amdgcn_mfma_f32_16x16x32_bf16(af[i], bfr[j], acc[i][j], 0, 0, 0);
    }

    #pragma unroll
    for (int i = 0; i < 4; i++)
        #pragma unroll
        for (int j = 0; j < 4; j++)
            #pragma unroll
            for (int r = 0; r < 4; r++) {
                int row = m0 + wm + i * 16 + quad * 4 + r;
                int col = n0 + wn + j * 16 + L15;
                float v = acc[i][j][r];
                if (OUT_BF16) Cb[(size_t)row * N + col] = f2bf(v);
                else          Cf[(size_t)row * N + col] = v;
            }
}

// ---------------------------------------------------------------- RoPE + reorder q,k
// Q gets (1/sqrt(96))*log2(e) folded in (flash softmax uses exp2).
// K written into PADDED+ROTATED tile layout: Kc[(b*NKV+kvh)*S + s][chunk(16)][8]
// with phys_chunk = (logical_chunk + s) & 15 -> bank-conflict-free LDS image.
__global__ void rope_reorder(const short* __restrict__ qkv, const int* __restrict__ pos_ids,
                             short* __restrict__ Q, short* __restrict__ Kc) {
    const int total = B_ * S_ * (NH + NKV) * HD;
    int idx = blockIdx.x * blockDim.x + threadIdx.x;
    int stride = gridDim.x * blockDim.x;
    for (; idx < total; idx += stride) {
        int d = idx % HD;
        int row = idx / HD;
        int h_all = row % (NH + NKV);
        int sb = row / (NH + NKV);
        int s = sb % S_;
        int b = sb / S_;
        int base = (b * S_ + s) * OPSZ;
        int off = (h_all < NH) ? (h_all * HD + d) : (H_ + (h_all - NH) * HD + d);
        float x = bf2f(qkv[base + off]);
        int delta = (d < 48) ? 48 : -48;
        float x2 = bf2f(qkv[base + off + delta]);
        int fi = d % 48;
        float inv = exp2f((float)fi * -0.2768273412f);   // 10000^(-fi/48)
        float theta = (float)pos_ids[b * S_ + s] * inv;
        float sn, cs;
        __sincosf(theta, &sn, &cs);
        float rot = (d < 48) ? -x2 : x2;
        float outv = x * cs + rot * sn;
        if (h_all < NH) {
            outv *= 0.14724438747f; // (1/sqrt(96)) * log2(e)
            Q[((size_t)(b * NH + h_all) * S_ + s) * HD + d] = f2bf(outv);
        } else {
            int kvh = h_all - NH;
            size_t kaddr = ((size_t)(b * NKV + kvh) * S_ + s) * 128
                         + (((d >> 3) + s) & 15) * 8 + (d & 7);
            Kc[kaddr] = f2bf(outv);
        }
    }
}

// ---------------------------------------------------------------- V transpose + swizzle (unchanged from R3, verified)
__global__ __launch_bounds__(256) void v_transpose(const short* __restrict__ qkv, short* __restrict__ Vt) {
    __shared__ short tile[64 * 104];
    int blk = blockIdx.x;
    int st  = blk & 31;
    int kvh = (blk >> 5) & 7;
    int b   = blk >> 8;
    int s0  = st * 64;
    int tid = threadIdx.x;
    #pragma unroll
    for (int i = 0; i < 3; i++) {
        int c = tid + i * 256;               // 64 rows x 12 chunks
        int row = c / 12, col8 = c % 12;
        *(short8*)&tile[row * 104 + col8 * 8] =
            *(const short8*)(qkv + (size_t)(b * S_ + s0 + row) * OPSZ + 3840 + kvh * HD + col8 * 8);
    }
    __syncthreads();
    #pragma unroll
    for (int i = 0; i < 3; i++) {
        int c = tid + i * 256;               // 96 rows x 8 chunks
        int d = c >> 3, col8 = c & 7;
        int chunk0 = (col8 - d) & 7;         // inverse rotation
        short8 v;
        #pragma unroll
        for (int j = 0; j < 8; j++) {
            int col0 = chunk0 * 8 + j;       // perm-space column
            int n = ((col0 >> 5) << 1) | (col0 & 1);
            int t = (col0 & 31) >> 1;
            v[j] = tile[(n * 16 + t) * 104 + d];
        }
        *(short8*)(Vt + ((size_t)(b * NKV + kvh) * HD + d) * S_ + s0 + col8 * 8) = v;
    }
}

// ---------------------------------------------------------------- causal flash attention v4
// BQ=128 (4 waves x 32 q-rows), BKV=64. DMA ping-pong, 1 barrier/iter.
// K staged from padded+rotated global layout (conflict-free). Row-sum of P via
// MFMA ones-column (V rows 96..111 constant); row-max via DPP rotate-reduce.
__global__ __launch_bounds__(256) void flash_attn(const short* __restrict__ Q, const short* __restrict__ Kc,
                                                  const short* __restrict__ Vt, short* __restrict__ attn) {
    __shared__ short kl[2][64 * 128];    // 32 KB  (padded+rotated DMA image)
    __shared__ short vl[2][112 * 64];    // 28 KB  (rows 96..111: ones-column block, constant)
    __shared__ short pl[4][32 * 72];     // 18.4 KB wave-private P
    const int x = blockIdx.x, h = blockIdx.y, b = blockIdx.z;
    const int kvh = h >> 2;
    const int tid = threadIdx.x, wave = tid >> 6, lane = tid & 63;
    const int L15 = lane & 15, quad = lane >> 4;

    // init constant V rows 96..111 (row 96 = 1.0, rest 0) in both buffers
    #pragma unroll
    for (int i = 0; i < 2; i++) {
        uint32_t* p = (uint32_t*)&vl[i][96 * 64];
        #pragma unroll
        for (int k = 0; k < 2; k++) {
            int idx = tid + k * 256;                 // 512 u32 per buffer
            p[idx] = (idx < 32) ? 0x3F803F80u : 0u;  // first 64 shorts = row 96
        }
    }

    const short* kbase = Kc + (size_t)(b * NKV + kvh) * S_ * 128;
    const short* vbase = Vt + (size_t)(b * NKV + kvh) * HD * S_;
    const int klane   = lane * 8;
    const int vrow_lo = lane >> 3;
    const int vcol    = (lane & 7) * 8;

    // loop-invariant LDS rotations (per-lane)
    int rotK[3], rotV[2];
    #pragma unroll
    for (int kk = 0; kk < 3; kk++) rotK[kk] = ((kk * 4 + quad + L15) & 15) * 8;
    #pragma unroll
    for (int kk = 0; kk < 2; kk++) rotV[kk] = ((kk * 4 + quad + L15) & 7) * 8;

    auto stage = [&](int kv0, int buf) {
        const short* ksrc = kbase + (size_t)kv0 * 128;
        #pragma unroll
        for (int i = 0; i < 4; i++) {
            int ck = wave * 4 + i;
            async_load16(ksrc + ck * 512 + klane, &kl[buf][ck * 512]);
        }
        #pragma unroll
        for (int i = 0; i < 3; i++) {
            int ck = wave * 3 + i;
            async_load16(vbase + (size_t)(ck * 8 + vrow_lo) * S_ + kv0 + vcol, &vl[buf][ck * 512]);
        }
    };

    #pragma unroll
    for (int pp = 0; pp < 2; pp++) {
        const int qt = pp ? x : (15 - x);
        const int q0 = qt * 128;
        const int jmax = 2 * qt + 2;

        short8 qf[2][3];
        #pragma unroll
        for (int mm = 0; mm < 2; mm++) {
            const short* qrow = Q + ((size_t)(b * NH + h) * S_ + q0 + wave * 32 + mm * 16 + L15) * HD;
            #pragma unroll
            for (int kk = 0; kk < 3; kk++) qf[mm][kk] = *(const short8*)(qrow + kk * 32 + quad * 8);
        }
        floatx4 o[2][7];                    // col 6 = row-sum accumulator (l)
        float m_r[2][4];
        #pragma unroll
        for (int mm = 0; mm < 2; mm++) {
            #pragma unroll
            for (int nn = 0; nn < 7; nn++) o[mm][nn] = (floatx4){0.f, 0.f, 0.f, 0.f};
            #pragma unroll
            for (int r = 0; r < 4; r++) m_r[mm][r] = -3.0e38f;
        }

        __syncthreads();                 // prior sub-problem's reads done; V const rows visible
        stage(0, 0);

        for (int j = 0; j < jmax; j++) {
            const int c = j & 1;
            const int kv0 = j * 64;
            __syncthreads();             // implicit vmcnt(0): DMA(j) landed; buf 1-c free
            if (j + 1 < jmax) stage(kv0 + 64, 1 - c);

            const short* klp = kl[c];
            const short* vlp = vl[c];

            floatx4 sacc[2][4];
            #pragma unroll
            for (int mm = 0; mm < 2; mm++)
                #pragma unroll
                for (int n = 0; n < 4; n++) sacc[mm][n] = (floatx4){0.f, 0.f, 0.f, 0.f};
            #pragma unroll
            for (int n = 0; n < 4; n++)
                #pragma unroll
                for (int kk = 0; kk < 3; kk++) {
                    short8 kf = *(const short8*)&klp[(n * 16 + L15) * 128 + rotK[kk]];
                    sacc[0][n] = __builtin_amdgcn_mfma_f32_16x16x32_bf16(qf[0][kk], kf, sacc[0][n], 0, 0, 0);
                    sacc[1][n] = __builtin_amdgcn_mfma_f32_16x16x32_bf16(qf[1][kk], kf, sacc[1][n], 0, 0, 0);
                }

            #pragma unroll
            for (int mm = 0; mm < 2; mm++) {
                const int tbase = q0 + wave * 32 + mm * 16;
                if (kv0 + 63 > tbase) {          // wave-uniform; mask kv > q
                    int qr_base = tbase + quad * 4;
                    #pragma unroll
                    for (int n = 0; n < 4; n++) {
                        int kv = kv0 + n * 16 + L15;
                        #pragma unroll
                        for (int r = 0; r < 4; r++)
                            if (kv > qr_base + r) sacc[mm][n][r] = -3.0e38f;
                    }
                }
                float alpha[4];
                #pragma unroll
                for (int r = 0; r < 4; r++) {
                    float mx = fmaxf(fmaxf(sacc[mm][0][r], sacc[mm][1][r]),
                                     fmaxf(sacc[mm][2][r], sacc[mm][3][r]));
                    mx = dpp_max16(mx);
                    float mn = fmaxf(m_r[mm][r], mx);
                    alpha[r] = fast_exp2(m_r[mm][r] - mn);
                    m_r[mm][r] = mn;
                }
                #pragma unroll
                for (int n = 0; n < 4; n++)
                    #pragma unroll
                    for (int r = 0; r < 4; r++)
                        sacc[mm][n][r] = fast_exp2(sacc[mm][n][r] - m_r[mm][r]);
                // P -> wave-private LDS, perm space, packed u32 (trunc)
                #pragma unroll
                for (int r = 0; r < 4; r++) {
                    int prow = mm * 16 + quad * 4 + r;
                    *(uint32_t*)&pl[wave][prow * 72 + 2 * L15]      = pk_bf_trunc(sacc[mm][0][r], sacc[mm][1][r]);
                    *(uint32_t*)&pl[wave][prow * 72 + 32 + 2 * L15] = pk_bf_trunc(sacc[mm][2][r], sacc[mm][3][r]);
                }
                // rescale O + l accumulator
                #pragma unroll
                for (int nn = 0; nn < 7; nn++)
                    #pragma unroll
                    for (int r = 0; r < 4; r++) o[mm][nn][r] *= alpha[r];
            }

            // PV in perm space (V rows chunk-rotated, baked in Vt); nn=6 = ones column -> l
            #pragma unroll
            for (int kk = 0; kk < 2; kk++) {
                short8 af0 = *(const short8*)&pl[wave][L15 * 72 + kk * 32 + quad * 8];
                short8 af1 = *(const short8*)&pl[wave][(16 + L15) * 72 + kk * 32 + quad * 8];
                #pragma unroll
                for (int nn = 0; nn < 7; nn++) {
                    short8 vf = *(const short8*)&vlp[(nn * 16 + L15) * 64 + rotV[kk]];
                    o[0][nn] = __builtin_amdgcn_mfma_f32_16x16x32_bf16(af0, vf, o[0][nn], 0, 0, 0);
                    o[1][nn] = __builtin_amdgcn_mfma_f32_16x16x32_bf16(af1, vf, o[1][nn], 0, 0, 0);
                }
            }
        }

        #pragma unroll
        for (int mm = 0; mm < 2; mm++) {
            float inv_l[4];
            #pragma unroll
            for (int r = 0; r < 4; r++) {
                float l = __shfl(o[mm][6][r], lane & 48);   // col 96 lives in L15==0
                inv_l[r] = 1.0f / l;
            }
            #pragma unroll
            for (int nn = 0; nn < 6; nn++)
                #pragma unroll
                for (int r = 0; r < 4; r++) {
                    float v = o[mm][nn][r] * inv_l[r];
                    int row = q0 + wave * 32 + mm * 16 + quad * 4 + r;
                    attn[((size_t)(b * S_) + row) * H_ + h * HD + nn * 16 + L15] = f2bf(v);
                }
        }
    }
}

// ---------------------------------------------------------------- launch
extern "C" void kernel_launch(void* const* d_in, const int* in_sizes, int n_in,
                              void* d_out, int out_size, void* d_ws, size_t ws_size,
                              hipStream_t stream) {
    const float* hid  = (const float*)d_in[0];
    const int*   pos  = (const int*)d_in[1];
    const float* wqkv = (const float*)d_in[2];
    const float* wo   = (const float*)d_in[3];
    float* out = (float*)d_out;
    char* ws = (char*)d_ws;

    short* hid_b  = (short*)(ws + 0L);          // 4096*3072 bf16 (later overlaid by attn_b)
    short* wqkv_b = (short*)(ws + 25165824L);   // 4608*3072 bf16
    short* wo_b   = (short*)(ws + 53477376L);   // 3072*3072 bf16
    short* qkv_b  = (short*)(ws + 72351744L);   // 4096*4608 bf16
    short* q_b    = (short*)(ws + 110100480L);  // [B,NH,S,HD] bf16
    short* k_b    = (short*)(ws + 135266304L);  // [B,NKV,S,128] bf16 padded+rotated (8.39MB)
    short* vt_b   = (short*)(ws + 143654912L);  // [B,NKV,HD,S] bf16 (swizzled, 6.29MB)
    short* attn_b = (short*)(ws + 0L);          // overlays hid_b (hid dead after QKV GEMM)

    cast3_f32_bf16<<<4096, 256, 0, stream>>>(hid, wqkv, wo, hid_b, wqkv_b, wo_b);

    gemm_bt<1><<<dim3(OPSZ / 128, MM / 128), 256, 0, stream>>>(hid_b, wqkv_b, nullptr, qkv_b, MM, OPSZ, H_);

    rope_reorder<<<8192, 256, 0, stream>>>(qkv_b, pos, q_b, k_b);
    v_transpose<<<512, 256, 0, stream>>>(qkv_b, vt_b);

    flash_attn<<<dim3(8, NH, B_), 256, 0, stream>>>(q_b, k_b, vt_b, attn_b);

    gemm_bt<0><<<dim3(H_ / 128, MM / 128), 256, 0, stream>>>(attn_b, wo_b, out, nullptr, MM, H_, H_);
}

// Round 5
// 567.517 us; speedup vs baseline: 1.5517x; 1.0297x over previous
//
#include <hip/hip_runtime.h>
#include <stdint.h>
#include <math.h>

// Problem constants (Phi3 attention block)
#define B_   2
#define S_   2048
#define H_   3072
#define NH   32
#define NKV  8
#define HD   96
#define OPSZ 4608          // NH*HD + 2*NKV*HD
#define MM   (B_*S_)       // 4096 token rows

typedef __attribute__((ext_vector_type(8))) short short8;
typedef __attribute__((ext_vector_type(4))) float floatx4;

__device__ __forceinline__ short f2bf(float f) {
    union { float f; uint32_t u; } v; v.f = f;
    uint32_t r = v.u + 0x7fffu + ((v.u >> 16) & 1u);   // RNE
    return (short)(r >> 16);
}
__device__ __forceinline__ float bf2f(short s) {
    union { uint32_t u; float f; } v; v.u = ((uint32_t)(uint16_t)s) << 16;
    return v.f;
}
// truncating bf16x2 pack (P in [0,1]; bias <= 2^-9 rel, numerator & denominator consistent)
__device__ __forceinline__ uint32_t pk_bf_trunc(float lo, float hi) {
    union { float f; uint32_t u; } a, b; a.f = lo; b.f = hi;
    return (a.u >> 16) | (b.u & 0xFFFF0000u);
}
// raw v_exp_f32 (base-2): skips OCML denorm-fixup tail; -3e38 input -> 0
__device__ __forceinline__ float fast_exp2(float x) {
    float r;
    asm volatile("v_exp_f32 %0, %1" : "=v"(r) : "v"(x));
    return r;
}
// max over the 16 lanes of a DPP row via row_ror rotate-reduce (pure VALU)
__device__ __forceinline__ float dpp_max16(float x) {
    union { float f; int i; } a, t;
    a.f = x;
    t.i = __builtin_amdgcn_update_dpp(0, a.i, 0x128, 0xF, 0xF, false); a.f = fmaxf(a.f, t.f);
    t.i = __builtin_amdgcn_update_dpp(0, a.i, 0x124, 0xF, 0xF, false); a.f = fmaxf(a.f, t.f);
    t.i = __builtin_amdgcn_update_dpp(0, a.i, 0x122, 0xF, 0xF, false); a.f = fmaxf(a.f, t.f);
    t.i = __builtin_amdgcn_update_dpp(0, a.i, 0x121, 0xF, 0xF, false); a.f = fmaxf(a.f, t.f);
    return a.f;
}

// async global->LDS, 16B per lane; lds dest is wave-uniform base + lane*16
__device__ __forceinline__ void async_load16(const void* g, void* l) {
    __builtin_amdgcn_global_load_lds(
        (const __attribute__((address_space(1))) void*)g,
        (__attribute__((address_space(3))) void*)l, 16, 0, 0);
}

// ---------------------------------------------------------------- merged casts fp32->bf16
#define CN1 (MM * H_ / 4)
#define CN2 (OPSZ * H_ / 4)
#define CN3 (H_ * H_ / 4)
__global__ void cast3_f32_bf16(const float* __restrict__ s1, const float* __restrict__ s2,
                               const float* __restrict__ s3, short* __restrict__ d1,
                               short* __restrict__ d2, short* __restrict__ d3) {
    int gid = blockIdx.x * blockDim.x + threadIdx.x;
    int stride = gridDim.x * blockDim.x;
    for (int i = gid; i < CN1; i += stride) {
        float4 v = ((const float4*)s1)[i];
        short4 o; o.x = f2bf(v.x); o.y = f2bf(v.y); o.z = f2bf(v.z); o.w = f2bf(v.w);
        ((short4*)d1)[i] = o;
    }
    for (int i = gid; i < CN2; i += stride) {
        float4 v = ((const float4*)s2)[i];
        short4 o; o.x = f2bf(v.x); o.y = f2bf(v.y); o.z = f2bf(v.z); o.w = f2bf(v.w);
        ((short4*)d2)[i] = o;
    }
    for (int i = gid; i < CN3; i += stride) {
        float4 v = ((const float4*)s3)[i];
        short4 o; o.x = f2bf(v.x); o.y = f2bf(v.y); o.z = f2bf(v.z); o.w = f2bf(v.w);
        ((short4*)d3)[i] = o;
    }
}

// ---------------------------------------------------------------- GEMM  C[M,N] = A[M,K] * B[N,K]^T
// v2: single-barrier DMA ping-pong K-loop (flash-v3 structure) + XCD supertile remap.
// 1D grid, num_m must be divisible by 8. id%8 pins an M-tile per XCD within a
// group-of-8 supertile: each XCD's L2 re-serves one A-tile across the N sweep.
template<int OUT_BF16>
__global__ __launch_bounds__(256) void gemm_bt(const short* __restrict__ A, const short* __restrict__ Bm,
                                               float* __restrict__ Cf, short* __restrict__ Cb,
                                               int M, int N, int K) {
    __shared__ short la[2][128 * 32];
    __shared__ short lb[2][128 * 32];
    const int tid  = threadIdx.x;
    const int wave = tid >> 6, lane = tid & 63;
    const int L15  = lane & 15, quad = lane >> 4;

    const int num_n = N >> 7;
    const int linear = blockIdx.x;
    const int group = linear / (8 * num_n);
    const int rem   = linear % (8 * num_n);
    const int m0 = (group * 8 + (rem & 7)) * 128;
    const int n0 = (rem >> 3) * 128;
    const int wm = (wave >> 1) * 64, wn = (wave & 1) * 64;

    // DMA geometry: wave w, instr t covers rows w*32+t*16..+16; lane -> (row=lane/4, chunk=lane%4)
    const int drow = wave * 32 + (lane >> 2);
    const int dcol = (lane & 3) * 8;
    const short* ga0 = A  + (size_t)(m0 + drow) * K + dcol;
    const short* ga1 = A  + (size_t)(m0 + drow + 16) * K + dcol;
    const short* gb0 = Bm + (size_t)(n0 + drow) * K + dcol;
    const short* gb1 = Bm + (size_t)(n0 + drow + 16) * K + dcol;
    const int lo0 = (wave * 32) * 32, lo1 = (wave * 32 + 16) * 32;

    floatx4 acc[4][4];
    for (int i = 0; i < 4; i++)
        for (int j = 0; j < 4; j++)
            acc[i][j] = (floatx4){0.f, 0.f, 0.f, 0.f};

    auto stage = [&](int k0, int buf) {
        async_load16(ga0 + k0, &la[buf][lo0]);
        async_load16(ga1 + k0, &la[buf][lo1]);
        async_load16(gb0 + k0, &lb[buf][lo0]);
        async_load16(gb1 + k0, &lb[buf][lo1]);
    };

    stage(0, 0);
    const int nk = K >> 5;
    for (int t = 0; t < nk; t++) {
        const int c = t & 1;
        __syncthreads();                       // drains DMA(t) (issued one phase ago); buf 1-c reads done
        if (t + 1 < nk) stage((t + 1) << 5, 1 - c);

        short8 af[4], bfr[4];
        #pragma unroll
        for (int i = 0; i < 4; i++)
            af[i] = *(const short8*)&la[c][(wm + i * 16 + L15) * 32 + quad * 8];
        #pragma unroll
        for (int j = 0; j < 4; j++)
            bfr[j] = *(const short8*)&lb[c][(wn + j * 16 + L15) * 32 + quad * 8];
        #pragma unroll
        for (int i = 0; i < 4; i++)
            #pragma unroll
            for (int j = 0; j < 4; j++)
                acc[i][j] = __builtin_amdgcn_mfma_f32_16x16x32_bf16(af[i], bfr[j], acc[i][j], 0, 0, 0);
    }

    // C/D layout: col = lane&15, row = quad*4 + reg
    #pragma unroll
    for (int i = 0; i < 4; i++)
        #pragma unroll
        for (int j = 0; j < 4; j++)
            #pragma unroll
            for (int r = 0; r < 4; r++) {
                int row = m0 + wm + i * 16 + quad * 4 + r;
                int col = n0 + wn + j * 16 + L15;
                float v = acc[i][j][r];
                if (OUT_BF16) Cb[(size_t)row * N + col] = f2bf(v);
                else          Cf[(size_t)row * N + col] = v;
            }
}

// ---------------------------------------------------------------- RoPE + reorder q,k
// Q gets (1/sqrt(96))*log2(e) folded in (flash softmax uses exp2).
// K written into PADDED+ROTATED tile layout: Kc[(b*NKV+kvh)*S + s][chunk(16)][8]
// with phys_chunk = (logical_chunk + s) & 15 -> bank-conflict-free LDS image.
__global__ void rope_reorder(const short* __restrict__ qkv, const int* __restrict__ pos_ids,
                             short* __restrict__ Q, short* __restrict__ Kc) {
    const int total = B_ * S_ * (NH + NKV) * HD;
    int idx = blockIdx.x * blockDim.x + threadIdx.x;
    int stride = gridDim.x * blockDim.x;
    for (; idx < total; idx += stride) {
        int d = idx % HD;
        int row = idx / HD;
        int h_all = row % (NH + NKV);
        int sb = row / (NH + NKV);
        int s = sb % S_;
        int b = sb / S_;
        int base = (b * S_ + s) * OPSZ;
        int off = (h_all < NH) ? (h_all * HD + d) : (H_ + (h_all - NH) * HD + d);
        float x = bf2f(qkv[base + off]);
        int delta = (d < 48) ? 48 : -48;
        float x2 = bf2f(qkv[base + off + delta]);
        int fi = d % 48;
        float inv = exp2f((float)fi * -0.2768273412f);   // 10000^(-fi/48)
        float theta = (float)pos_ids[b * S_ + s] * inv;
        float sn, cs;
        __sincosf(theta, &sn, &cs);
        float rot = (d < 48) ? -x2 : x2;
        float outv = x * cs + rot * sn;
        if (h_all < NH) {
            outv *= 0.14724438747f; // (1/sqrt(96)) * log2(e)
            Q[((size_t)(b * NH + h_all) * S_ + s) * HD + d] = f2bf(outv);
        } else {
            int kvh = h_all - NH;
            size_t kaddr = ((size_t)(b * NKV + kvh) * S_ + s) * 128
                         + (((d >> 3) + s) & 15) * 8 + (d & 7);
            Kc[kaddr] = f2bf(outv);
        }
    }
}

// ---------------------------------------------------------------- V transpose + swizzle (verified)
__global__ __launch_bounds__(256) void v_transpose(const short* __restrict__ qkv, short* __restrict__ Vt) {
    __shared__ short tile[64 * 104];
    int blk = blockIdx.x;
    int st  = blk & 31;
    int kvh = (blk >> 5) & 7;
    int b   = blk >> 8;
    int s0  = st * 64;
    int tid = threadIdx.x;
    #pragma unroll
    for (int i = 0; i < 3; i++) {
        int c = tid + i * 256;               // 64 rows x 12 chunks
        int row = c / 12, col8 = c % 12;
        *(short8*)&tile[row * 104 + col8 * 8] =
            *(const short8*)(qkv + (size_t)(b * S_ + s0 + row) * OPSZ + 3840 + kvh * HD + col8 * 8);
    }
    __syncthreads();
    #pragma unroll
    for (int i = 0; i < 3; i++) {
        int c = tid + i * 256;               // 96 rows x 8 chunks
        int d = c >> 3, col8 = c & 7;
        int chunk0 = (col8 - d) & 7;         // inverse rotation
        short8 v;
        #pragma unroll
        for (int j = 0; j < 8; j++) {
            int col0 = chunk0 * 8 + j;       // perm-space column
            int n = ((col0 >> 5) << 1) | (col0 & 1);
            int t = (col0 & 31) >> 1;
            v[j] = tile[(n * 16 + t) * 104 + d];
        }
        *(short8*)(Vt + ((size_t)(b * NKV + kvh) * HD + d) * S_ + s0 + col8 * 8) = v;
    }
}

// ---------------------------------------------------------------- causal flash attention v4 (unchanged from R3)
__global__ __launch_bounds__(256) void flash_attn(const short* __restrict__ Q, const short* __restrict__ Kc,
                                                  const short* __restrict__ Vt, short* __restrict__ attn) {
    __shared__ short kl[2][64 * 128];    // 32 KB  (padded+rotated DMA image)
    __shared__ short vl[2][112 * 64];    // 28 KB  (rows 96..111: ones-column block, constant)
    __shared__ short pl[4][32 * 72];     // 18.4 KB wave-private P
    const int x = blockIdx.x, h = blockIdx.y, b = blockIdx.z;
    const int kvh = h >> 2;
    const int tid = threadIdx.x, wave = tid >> 6, lane = tid & 63;
    const int L15 = lane & 15, quad = lane >> 4;

    #pragma unroll
    for (int i = 0; i < 2; i++) {
        uint32_t* p = (uint32_t*)&vl[i][96 * 64];
        #pragma unroll
        for (int k = 0; k < 2; k++) {
            int idx = tid + k * 256;
            p[idx] = (idx < 32) ? 0x3F803F80u : 0u;
        }
    }

    const short* kbase = Kc + (size_t)(b * NKV + kvh) * S_ * 128;
    const short* vbase = Vt + (size_t)(b * NKV + kvh) * HD * S_;
    const int klane   = lane * 8;
    const int vrow_lo = lane >> 3;
    const int vcol    = (lane & 7) * 8;

    int rotK[3], rotV[2];
    #pragma unroll
    for (int kk = 0; kk < 3; kk++) rotK[kk] = ((kk * 4 + quad + L15) & 15) * 8;
    #pragma unroll
    for (int kk = 0; kk < 2; kk++) rotV[kk] = ((kk * 4 + quad + L15) & 7) * 8;

    auto stage = [&](int kv0, int buf) {
        const short* ksrc = kbase + (size_t)kv0 * 128;
        #pragma unroll
        for (int i = 0; i < 4; i++) {
            int ck = wave * 4 + i;
            async_load16(ksrc + ck * 512 + klane, &kl[buf][ck * 512]);
        }
        #pragma unroll
        for (int i = 0; i < 3; i++) {
            int ck = wave * 3 + i;
            async_load16(vbase + (size_t)(ck * 8 + vrow_lo) * S_ + kv0 + vcol, &vl[buf][ck * 512]);
        }
    };

    #pragma unroll
    for (int pp = 0; pp < 2; pp++) {
        const int qt = pp ? x : (15 - x);
        const int q0 = qt * 128;
        const int jmax = 2 * qt + 2;

        short8 qf[2][3];
        #pragma unroll
        for (int mm = 0; mm < 2; mm++) {
            const short* qrow = Q + ((size_t)(b * NH + h) * S_ + q0 + wave * 32 + mm * 16 + L15) * HD;
            #pragma unroll
            for (int kk = 0; kk < 3; kk++) qf[mm][kk] = *(const short8*)(qrow + kk * 32 + quad * 8);
        }
        floatx4 o[2][7];                    // col 6 = row-sum accumulator (l)
        float m_r[2][4];
        #pragma unroll
        for (int mm = 0; mm < 2; mm++) {
            #pragma unroll
            for (int nn = 0; nn < 7; nn++) o[mm][nn] = (floatx4){0.f, 0.f, 0.f, 0.f};
            #pragma unroll
            for (int r = 0; r < 4; r++) m_r[mm][r] = -3.0e38f;
        }

        __syncthreads();
        stage(0, 0);

        for (int j = 0; j < jmax; j++) {
            const int c = j & 1;
            const int kv0 = j * 64;
            __syncthreads();
            if (j + 1 < jmax) stage(kv0 + 64, 1 - c);

            const short* klp = kl[c];
            const short* vlp = vl[c];

            floatx4 sacc[2][4];
            #pragma unroll
            for (int mm = 0; mm < 2; mm++)
                #pragma unroll
                for (int n = 0; n < 4; n++) sacc[mm][n] = (floatx4){0.f, 0.f, 0.f, 0.f};
            #pragma unroll
            for (int n = 0; n < 4; n++)
                #pragma unroll
                for (int kk = 0; kk < 3; kk++) {
                    short8 kf = *(const short8*)&klp[(n * 16 + L15) * 128 + rotK[kk]];
                    sacc[0][n] = __builtin_amdgcn_mfma_f32_16x16x32_bf16(qf[0][kk], kf, sacc[0][n], 0, 0, 0);
                    sacc[1][n] = __builtin_amdgcn_mfma_f32_16x16x32_bf16(qf[1][kk], kf, sacc[1][n], 0, 0, 0);
                }

            #pragma unroll
            for (int mm = 0; mm < 2; mm++) {
                const int tbase = q0 + wave * 32 + mm * 16;
                if (kv0 + 63 > tbase) {
                    int qr_base = tbase + quad * 4;
                    #pragma unroll
                    for (int n = 0; n < 4; n++) {
                        int kv = kv0 + n * 16 + L15;
                        #pragma unroll
                        for (int r = 0; r < 4; r++)
                            if (kv > qr_base + r) sacc[mm][n][r] = -3.0e38f;
                    }
                }
                float alpha[4];
                #pragma unroll
                for (int r = 0; r < 4; r++) {
                    float mx = fmaxf(fmaxf(sacc[mm][0][r], sacc[mm][1][r]),
                                     fmaxf(sacc[mm][2][r], sacc[mm][3][r]));
                    mx = dpp_max16(mx);
                    float mn = fmaxf(m_r[mm][r], mx);
                    alpha[r] = fast_exp2(m_r[mm][r] - mn);
                    m_r[mm][r] = mn;
                }
                #pragma unroll
                for (int n = 0; n < 4; n++)
                    #pragma unroll
                    for (int r = 0; r < 4; r++)
                        sacc[mm][n][r] = fast_exp2(sacc[mm][n][r] - m_r[mm][r]);
                #pragma unroll
                for (int r = 0; r < 4; r++) {
                    int prow = mm * 16 + quad * 4 + r;
                    *(uint32_t*)&pl[wave][prow * 72 + 2 * L15]      = pk_bf_trunc(sacc[mm][0][r], sacc[mm][1][r]);
                    *(uint32_t*)&pl[wave][prow * 72 + 32 + 2 * L15] = pk_bf_trunc(sacc[mm][2][r], sacc[mm][3][r]);
                }
                #pragma unroll
                for (int nn = 0; nn < 7; nn++)
                    #pragma unroll
                    for (int r = 0; r < 4; r++) o[mm][nn][r] *= alpha[r];
            }

            #pragma unroll
            for (int kk = 0; kk < 2; kk++) {
                short8 af0 = *(const short8*)&pl[wave][L15 * 72 + kk * 32 + quad * 8];
                short8 af1 = *(const short8*)&pl[wave][(16 + L15) * 72 + kk * 32 + quad * 8];
                #pragma unroll
                for (int nn = 0; nn < 7; nn++) {
                    short8 vf = *(const short8*)&vlp[(nn * 16 + L15) * 64 + rotV[kk]];
                    o[0][nn] = __builtin_amdgcn_mfma_f32_16x16x32_bf16(af0, vf, o[0][nn], 0, 0, 0);
                    o[1][nn] = __builtin_amdgcn_mfma_f32_16x16x32_bf16(af1, vf, o[1][nn], 0, 0, 0);
                }
            }
        }

        #pragma unroll
        for (int mm = 0; mm < 2; mm++) {
            float inv_l[4];
            #pragma unroll
            for (int r = 0; r < 4; r++) {
                float l = __shfl(o[mm][6][r], lane & 48);   // col 96 lives in L15==0
                inv_l[r] = 1.0f / l;
            }
            #pragma unroll
            for (int nn = 0; nn < 6; nn++)
                #pragma unroll
                for (int r = 0; r < 4; r++) {
                    float v = o[mm][nn][r] * inv_l[r];
                    int row = q0 + wave * 32 + mm * 16 + quad * 4 + r;
                    attn[((size_t)(b * S_) + row) * H_ + h * HD + nn * 16 + L15] = f2bf(v);
                }
        }
    }
}

// ---------------------------------------------------------------- launch
extern "C" void kernel_launch(void* const* d_in, const int* in_sizes, int n_in,
                              void* d_out, int out_size, void* d_ws, size_t ws_size,
                              hipStream_t stream) {
    const float* hid  = (const float*)d_in[0];
    const int*   pos  = (const int*)d_in[1];
    const float* wqkv = (const float*)d_in[2];
    const float* wo   = (const float*)d_in[3];
    float* out = (float*)d_out;
    char* ws = (char*)d_ws;

    short* hid_b  = (short*)(ws + 0L);          // 4096*3072 bf16 (later overlaid by attn_b)
    short* wqkv_b = (short*)(ws + 25165824L);   // 4608*3072 bf16
    short* wo_b   = (short*)(ws + 53477376L);   // 3072*3072 bf16
    short* qkv_b  = (short*)(ws + 72351744L);   // 4096*4608 bf16
    short* q_b    = (short*)(ws + 110100480L);  // [B,NH,S,HD] bf16
    short* k_b    = (short*)(ws + 135266304L);  // [B,NKV,S,128] bf16 padded+rotated (8.39MB)
    short* vt_b   = (short*)(ws + 143654912L);  // [B,NKV,HD,S] bf16 (swizzled, 6.29MB)
    short* attn_b = (short*)(ws + 0L);          // overlays hid_b (hid dead after QKV GEMM)

    cast3_f32_bf16<<<4096, 256, 0, stream>>>(hid, wqkv, wo, hid_b, wqkv_b, wo_b);

    gemm_bt<1><<<(OPSZ / 128) * (MM / 128), 256, 0, stream>>>(hid_b, wqkv_b, nullptr, qkv_b, MM, OPSZ, H_);

    rope_reorder<<<8192, 256, 0, stream>>>(qkv_b, pos, q_b, k_b);
    v_transpose<<<512, 256, 0, stream>>>(qkv_b, vt_b);

    flash_attn<<<dim3(8, NH, B_), 256, 0, stream>>>(q_b, k_b, vt_b, attn_b);

    gemm_bt<0><<<(H_ / 128) * (MM / 128), 256, 0, stream>>>(attn_b, wo_b, out, nullptr, MM, H_, H_);
}